// Round 1
// baseline (103.987 us; speedup 1.0000x reference)
//
#include <hip/hip_runtime.h>
#include <stdint.h>

#define C   32
#define H   160
#define W   160
#define NB  32
#define HW  (H * W)          // 25600
#define CHW (C * HW)         // 819200
#define NPIX (NB * HW)       // 819200

// d_ws layout (uint32 units):
// [0,288)    w3bits  [oc*9 + kh*3 + kw], bit ic = (w3<0)
// [288,320)  w1bits  [oc], bit ic = (w1<0)
// [320,352)  scale3 (f32)   [352,384) shift3
// [384,416)  scale1 (f32)   [416,448) shift1
// [448,448+NPIX) xbits [n*HW + h*W + w], bit c = (x<0)

__global__ void pack_params(const float* __restrict__ w3,
                            const float* __restrict__ g3, const float* __restrict__ b3,
                            const float* __restrict__ m3, const float* __restrict__ v3,
                            const float* __restrict__ w1,
                            const float* __restrict__ g1, const float* __restrict__ b1,
                            const float* __restrict__ m1, const float* __restrict__ v1,
                            uint32_t* __restrict__ wsu) {
    int t = threadIdx.x;
    if (t < 288) {
        int oc = t / 9, tap = t % 9;
        uint32_t bits = 0;
#pragma unroll
        for (int ic = 0; ic < 32; ++ic)
            bits |= (w3[oc * 288 + ic * 9 + tap] < 0.0f) ? (1u << ic) : 0u;
        wsu[t] = bits;
    } else if (t < 320) {
        int oc = t - 288;
        uint32_t bits = 0;
#pragma unroll
        for (int ic = 0; ic < 32; ++ic)
            bits |= (w1[oc * 32 + ic] < 0.0f) ? (1u << ic) : 0u;
        wsu[288 + oc] = bits;
        float* f = (float*)wsu;
        float inv3 = g3[oc] * rsqrtf(v3[oc] + 1e-5f);
        f[320 + oc] = inv3;
        f[352 + oc] = b3[oc] - m3[oc] * inv3;
        float inv1 = g1[oc] * rsqrtf(v1[oc] + 1e-5f);
        f[384 + oc] = inv1;
        f[416 + oc] = b1[oc] - m1[oc] * inv1;
    }
}

__global__ __launch_bounds__(256) void pack_x(const float* __restrict__ x,
                                              uint32_t* __restrict__ xbits) {
    int i = blockIdx.x * blockDim.x + threadIdx.x;   // quad index
    if (i >= NPIX / 4) return;
    int p = i * 4;
    int n = p / HW;
    int r = p % HW;
    const float* xp = x + n * CHW + r;
    uint32_t b0 = 0, b1 = 0, b2 = 0, b3 = 0;
#pragma unroll
    for (int c = 0; c < 32; ++c) {
        float4 v = *reinterpret_cast<const float4*>(xp + c * HW);
        b0 |= (v.x < 0.0f) ? (1u << c) : 0u;
        b1 |= (v.y < 0.0f) ? (1u << c) : 0u;
        b2 |= (v.z < 0.0f) ? (1u << c) : 0u;
        b3 |= (v.w < 0.0f) ? (1u << c) : 0u;
    }
    *reinterpret_cast<uint4*>(xbits + p) = make_uint4(b0, b1, b2, b3);
}

__global__ __launch_bounds__(256) void fused_block(const float* __restrict__ x,
                                                   const uint32_t* __restrict__ wsu,
                                                   float* __restrict__ out) {
    __shared__ uint32_t swb3[288];
    __shared__ uint32_t swb1[32];
    __shared__ float    sp[128];   // [0,32) sc3, [32,64) sh3, [64,96) sc1, [96,128) sh1

    {
        int t = threadIdx.x;
        if (t < 256) swb3[t] = wsu[t];
        if (t < 32) { swb3[256 + t] = wsu[256 + t]; swb1[t] = wsu[288 + t]; }
        if (t < 128) sp[t] = ((const float*)wsu)[320 + t];
    }
    __syncthreads();

    int pi = blockIdx.x * blockDim.x + threadIdx.x;   // pixel-pair index
    if (pi >= NPIX / 2) return;
    int p0  = pi * 2;
    int n   = p0 / HW;
    int rem = p0 % HW;
    int h   = rem / W;
    int w   = rem % W;          // even; pair covers columns w, w+1

    const uint32_t* xbn = wsu + 448 + n * HW;

    // 3x4 xbits neighborhood: rows h-1..h+1, cols w-1..w+2
    uint32_t nb[3][4];
    const bool r0ok = (h > 0), r2ok = (h < H - 1);
    const bool c0ok = (w > 0), c3ok = (w < W - 2);
#pragma unroll
    for (int r = 0; r < 3; ++r) {
        bool rok = (r == 0) ? r0ok : (r == 2) ? r2ok : true;
        const uint32_t* rp = xbn + (h + r - 1) * W + w;
        if (rok) {
            nb[r][0] = c0ok ? rp[-1] : 0u;
            nb[r][1] = rp[0];
            nb[r][2] = rp[1];
            nb[r][3] = c3ok ? rp[2] : 0u;
        } else {
            nb[r][0] = 0u; nb[r][1] = 0u; nb[r][2] = 0u; nb[r][3] = 0u;
        }
    }

    const float* xrow = x + n * CHW + h * W + w;
    float y0[32], y1[32];

    if (r0ok && r2ok && c0ok && c3ok) {
        // interior fast path: conv = 288 - 2*sum(popc)
#pragma unroll
        for (int oc = 0; oc < 32; ++oc) {
            int s0 = 0, s1 = 0;
#pragma unroll
            for (int r = 0; r < 3; ++r) {
#pragma unroll
                for (int c = 0; c < 3; ++c) {
                    uint32_t wv = swb3[oc * 9 + r * 3 + c];
                    s0 += __popc(nb[r][c] ^ wv);
                    s1 += __popc(nb[r][c + 1] ^ wv);
                }
            }
            float sc = sp[oc], sh = sp[32 + oc];
            float2 xv = *reinterpret_cast<const float2*>(xrow + oc * HW);
            y0[oc] = fmaf((float)(288 - 2 * s0), sc, sh) + xv.x;
            y1[oc] = fmaf((float)(288 - 2 * s1), sc, sh) + xv.y;
        }
    } else {
        // border path: per-tap masked accumulate of (32 - 2*popc)
        int cm0 = c0ok ? -1 : 0, cm3 = c3ok ? -1 : 0;
        int m[3][4];
#pragma unroll
        for (int r = 0; r < 3; ++r) {
            bool rok = (r == 0) ? r0ok : (r == 2) ? r2ok : true;
            int rm = rok ? -1 : 0;
            m[r][0] = rm & cm0; m[r][1] = rm; m[r][2] = rm; m[r][3] = rm & cm3;
        }
#pragma unroll
        for (int oc = 0; oc < 32; ++oc) {
            int s0 = 0, s1 = 0;
#pragma unroll
            for (int r = 0; r < 3; ++r) {
#pragma unroll
                for (int c = 0; c < 3; ++c) {
                    uint32_t wv = swb3[oc * 9 + r * 3 + c];
                    s0 += (32 - 2 * __popc(nb[r][c] ^ wv)) & m[r][c];
                    s1 += (32 - 2 * __popc(nb[r][c + 1] ^ wv)) & m[r][c + 1];
                }
            }
            float sc = sp[oc], sh = sp[32 + oc];
            float2 xv = *reinterpret_cast<const float2*>(xrow + oc * HW);
            y0[oc] = fmaf((float)s0, sc, sh) + xv.x;
            y1[oc] = fmaf((float)s1, sc, sh) + xv.y;
        }
    }

    // block 2: pack sign(y), 1x1 binary conv, BN, residual
    uint32_t yb0 = 0, yb1 = 0;
#pragma unroll
    for (int oc = 0; oc < 32; ++oc) {
        yb0 |= (y0[oc] < 0.0f) ? (1u << oc) : 0u;
        yb1 |= (y1[oc] < 0.0f) ? (1u << oc) : 0u;
    }
    float* orow = out + n * CHW + h * W + w;
#pragma unroll
    for (int oc = 0; oc < 32; ++oc) {
        float sc = sp[64 + oc], sh = sp[96 + oc];
        int c0 = 32 - 2 * __popc(yb0 ^ swb1[oc]);
        int c1 = 32 - 2 * __popc(yb1 ^ swb1[oc]);
        float2 zv;
        zv.x = fmaf((float)c0, sc, sh) + y0[oc];
        zv.y = fmaf((float)c1, sc, sh) + y1[oc];
        *reinterpret_cast<float2*>(orow + oc * HW) = zv;
    }
}

extern "C" void kernel_launch(void* const* d_in, const int* in_sizes, int n_in,
                              void* d_out, int out_size, void* d_ws, size_t ws_size,
                              hipStream_t stream) {
    const float* x  = (const float*)d_in[0];
    const float* w3 = (const float*)d_in[1];
    const float* g3 = (const float*)d_in[2];
    const float* b3 = (const float*)d_in[3];
    const float* m3 = (const float*)d_in[4];
    const float* v3 = (const float*)d_in[5];
    const float* w1 = (const float*)d_in[6];
    const float* g1 = (const float*)d_in[7];
    const float* b1 = (const float*)d_in[8];
    const float* m1 = (const float*)d_in[9];
    const float* v1 = (const float*)d_in[10];
    float* out = (float*)d_out;
    uint32_t* wsu = (uint32_t*)d_ws;

    pack_params<<<1, 320, 0, stream>>>(w3, g3, b3, m3, v3, w1, g1, b1, m1, v1, wsu);
    pack_x<<<NPIX / 4 / 256, 256, 0, stream>>>(x, wsu + 448);
    fused_block<<<NPIX / 2 / 256, 256, 0, stream>>>(x, wsu, out);
}

// Round 2
// 84.432 us; speedup vs baseline: 1.2316x; 1.2316x over previous
//
#include <hip/hip_runtime.h>
#include <stdint.h>

#define C   32
#define H   160
#define W   160
#define NB  32
#define HW  (H * W)          // 25600
#define CHW (C * HW)         // 819200
#define NPIX (NB * HW)       // 819200
#define XBOFF 448            // xbits offset in d_ws (u32 units)

// d_ws layout (uint32 units):
// [0,288)    w3bits  [oc*9 + kh*3 + kw], bit ic = (w3<0)
// [288,320)  w1bits  [oc], bit ic = (w1<0)
// [320,352)  scale3 (f32)   [352,384) shift3
// [384,416)  scale1 (f32)   [416,448) shift1
// [448,448+NPIX) xbits [n*HW + h*W + w], bit c = (x<0)

__global__ void pack_params(const float* __restrict__ w3,
                            const float* __restrict__ g3, const float* __restrict__ b3,
                            const float* __restrict__ m3, const float* __restrict__ v3,
                            const float* __restrict__ w1,
                            const float* __restrict__ g1, const float* __restrict__ b1,
                            const float* __restrict__ m1, const float* __restrict__ v1,
                            uint32_t* __restrict__ wsu) {
    int t = threadIdx.x;
    if (t < 288) {
        int oc = t / 9, tap = t % 9;
        uint32_t bits = 0;
#pragma unroll
        for (int ic = 0; ic < 32; ++ic)
            bits |= (w3[oc * 288 + ic * 9 + tap] < 0.0f) ? (1u << ic) : 0u;
        wsu[t] = bits;
    } else if (t < 320) {
        int oc = t - 288;
        uint32_t bits = 0;
#pragma unroll
        for (int ic = 0; ic < 32; ++ic)
            bits |= (w1[oc * 32 + ic] < 0.0f) ? (1u << ic) : 0u;
        wsu[288 + oc] = bits;
        float* f = (float*)wsu;
        float inv3 = g3[oc] * rsqrtf(v3[oc] + 1e-5f);
        f[320 + oc] = inv3;
        f[352 + oc] = b3[oc] - m3[oc] * inv3;
        float inv1 = g1[oc] * rsqrtf(v1[oc] + 1e-5f);
        f[384 + oc] = inv1;
        f[416 + oc] = b1[oc] - m1[oc] * inv1;
    }
}

__global__ __launch_bounds__(256) void pack_x(const float* __restrict__ x,
                                              uint32_t* __restrict__ xbits) {
    int i = blockIdx.x * blockDim.x + threadIdx.x;   // quad index
    if (i >= NPIX / 4) return;
    int p = i * 4;
    int n = p / HW;
    int r = p % HW;
    const float* xp = x + n * CHW + r;
    uint32_t b0 = 0, b1 = 0, b2 = 0, b3 = 0;
#pragma unroll
    for (int c = 0; c < 32; ++c) {
        float4 v = *reinterpret_cast<const float4*>(xp + c * HW);
        b0 |= (v.x < 0.0f) ? (1u << c) : 0u;
        b1 |= (v.y < 0.0f) ? (1u << c) : 0u;
        b2 |= (v.z < 0.0f) ? (1u << c) : 0u;
        b3 |= (v.w < 0.0f) ? (1u << c) : 0u;
    }
    *reinterpret_cast<uint4*>(xbits + p) = make_uint4(b0, b1, b2, b3);
}

// Main kernel: interior formula for ALL pixels, no branches, no LDS.
// Border pixels get wrong values here (clamped bit reads) and are
// overwritten by border_fix afterwards (stream-ordered).
__global__ __launch_bounds__(256) void fused_main(const float* __restrict__ x,
                                                  const uint32_t* __restrict__ wsu,
                                                  float* __restrict__ out) {
    const float* wf = (const float*)wsu;
    int pi = blockIdx.x * blockDim.x + threadIdx.x;  // pixel-pair index, exact grid
    int p0  = pi * 2;
    int n   = p0 / HW;
    int rem = p0 % HW;
    int h   = rem / W;
    int w   = rem % W;          // even; pair covers columns w, w+1

    const uint32_t* xbn = wsu + XBOFF + n * HW;

    // clamped row/col indices: all reads stay inside this image's bit plane.
    // Clamping only corrupts values for border pixels (overwritten later).
    int hm1 = (h > 0) ? h - 1 : 0;
    int hp1 = (h < H - 1) ? h + 1 : H - 1;
    int wm1 = (w > 0) ? w - 1 : 0;
    int wp2 = (w < W - 2) ? w + 2 : W - 1;

    uint32_t nb[3][4];
    {
        const uint32_t* r0 = xbn + hm1 * W;
        const uint32_t* r1 = xbn + h   * W;
        const uint32_t* r2 = xbn + hp1 * W;
        nb[0][0] = r0[wm1]; nb[0][1] = r0[w]; nb[0][2] = r0[w + 1]; nb[0][3] = r0[wp2];
        nb[1][0] = r1[wm1]; nb[1][1] = r1[w]; nb[1][2] = r1[w + 1]; nb[1][3] = r1[wp2];
        nb[2][0] = r2[wm1]; nb[2][1] = r2[w]; nb[2][2] = r2[w + 1]; nb[2][3] = r2[wp2];
    }

    const float* xrow = x + n * CHW + h * W + w;
    float y0[32], y1[32];

#pragma unroll
    for (int oc = 0; oc < 32; ++oc) {
        int s0 = 0, s1 = 0;
#pragma unroll
        for (int r = 0; r < 3; ++r) {
#pragma unroll
            for (int c = 0; c < 3; ++c) {
                uint32_t wv = wsu[oc * 9 + r * 3 + c];   // uniform -> s_load
                s0 += __popc(nb[r][c] ^ wv);
                s1 += __popc(nb[r][c + 1] ^ wv);
            }
        }
        float sc = wf[320 + oc], sh = wf[352 + oc];      // uniform -> s_load
        float2 xv = *reinterpret_cast<const float2*>(xrow + oc * HW);
        y0[oc] = fmaf((float)(288 - 2 * s0), sc, sh) + xv.x;
        y1[oc] = fmaf((float)(288 - 2 * s1), sc, sh) + xv.y;
    }

    uint32_t yb0 = 0, yb1 = 0;
#pragma unroll
    for (int oc = 0; oc < 32; ++oc) {
        yb0 |= (y0[oc] < 0.0f) ? (1u << oc) : 0u;
        yb1 |= (y1[oc] < 0.0f) ? (1u << oc) : 0u;
    }
    float* orow = out + n * CHW + h * W + w;
#pragma unroll
    for (int oc = 0; oc < 32; ++oc) {
        float sc = wf[384 + oc], sh = wf[416 + oc];
        int c0 = 32 - 2 * __popc(yb0 ^ wsu[288 + oc]);
        int c1 = 32 - 2 * __popc(yb1 ^ wsu[288 + oc]);
        float2 zv;
        zv.x = fmaf((float)c0, sc, sh) + y0[oc];
        zv.y = fmaf((float)c1, sc, sh) + y1[oc];
        *reinterpret_cast<float2*>(orow + oc * HW) = zv;
    }
}

// Recompute border pixels exactly (true zero-padding masks) and overwrite.
// 636 border pixels per image * 32 images = 20352 threads.
__global__ __launch_bounds__(256) void border_fix(const float* __restrict__ x,
                                                  const uint32_t* __restrict__ wsu,
                                                  float* __restrict__ out) {
    const float* wf = (const float*)wsu;
    int t = blockIdx.x * blockDim.x + threadIdx.x;
    if (t >= NB * 636) return;
    int n = t / 636, idx = t % 636;
    int h, w;
    if (idx < 160)      { h = 0;         w = idx; }
    else if (idx < 320) { h = H - 1;     w = idx - 160; }
    else if (idx < 478) { h = idx - 319; w = 0; }       // h = 1..158
    else                { h = idx - 477; w = W - 1; }   // h = 1..158

    const uint32_t* xbn = wsu + XBOFF + n * HW;
    uint32_t nb[3][3];
    int m[3][3];
#pragma unroll
    for (int r = 0; r < 3; ++r) {
        int hh = h + r - 1;
        bool rok = (hh >= 0) && (hh < H);
#pragma unroll
        for (int c = 0; c < 3; ++c) {
            int ww = w + c - 1;
            bool ok = rok && (ww >= 0) && (ww < W);
            m[r][c]  = ok ? -1 : 0;
            nb[r][c] = ok ? xbn[hh * W + ww] : 0u;
        }
    }

    const float* xp = x + n * CHW + h * W + w;
    float y[32];
    uint32_t yb = 0;
#pragma unroll
    for (int oc = 0; oc < 32; ++oc) {
        int s = 0;
#pragma unroll
        for (int r = 0; r < 3; ++r) {
#pragma unroll
            for (int c = 0; c < 3; ++c) {
                uint32_t wv = wsu[oc * 9 + r * 3 + c];
                s += (32 - 2 * __popc(nb[r][c] ^ wv)) & m[r][c];
            }
        }
        float sc = wf[320 + oc], sh = wf[352 + oc];
        y[oc] = fmaf((float)s, sc, sh) + xp[oc * HW];
        yb |= (y[oc] < 0.0f) ? (1u << oc) : 0u;
    }
    float* op = out + n * CHW + h * W + w;
#pragma unroll
    for (int oc = 0; oc < 32; ++oc) {
        float sc = wf[384 + oc], sh = wf[416 + oc];
        int cc = 32 - 2 * __popc(yb ^ wsu[288 + oc]);
        op[oc * HW] = fmaf((float)cc, sc, sh) + y[oc];
    }
}

extern "C" void kernel_launch(void* const* d_in, const int* in_sizes, int n_in,
                              void* d_out, int out_size, void* d_ws, size_t ws_size,
                              hipStream_t stream) {
    const float* x  = (const float*)d_in[0];
    const float* w3 = (const float*)d_in[1];
    const float* g3 = (const float*)d_in[2];
    const float* b3 = (const float*)d_in[3];
    const float* m3 = (const float*)d_in[4];
    const float* v3 = (const float*)d_in[5];
    const float* w1 = (const float*)d_in[6];
    const float* g1 = (const float*)d_in[7];
    const float* b1 = (const float*)d_in[8];
    const float* m1 = (const float*)d_in[9];
    const float* v1 = (const float*)d_in[10];
    float* out = (float*)d_out;
    uint32_t* wsu = (uint32_t*)d_ws;

    pack_params<<<1, 320, 0, stream>>>(w3, g3, b3, m3, v3, w1, g1, b1, m1, v1, wsu);
    pack_x<<<NPIX / 4 / 256, 256, 0, stream>>>(x, wsu + XBOFF);
    fused_main<<<NPIX / 2 / 256, 256, 0, stream>>>(x, wsu, out);
    border_fix<<<(NB * 636 + 255) / 256, 256, 0, stream>>>(x, wsu, out);
}